// Round 1
// baseline (704.469 us; speedup 1.0000x reference)
//
#include <hip/hip_runtime.h>

#define N_NODES 100000
#define D 64
#define NPAD 100352   // N_NODES rounded up to multiple of 1024
#define CHUNK 1024

// ---------------- CSR build ----------------

__global__ __launch_bounds__(256) void k_count(const int* __restrict__ dst,
                                               int* __restrict__ cnt, int E) {
    int e = blockIdx.x * 256 + threadIdx.x;
    if (e < E) atomicAdd(&cnt[dst[e]], 1);
}

// Per-block exclusive scan over 1024 ints; writes partial scan + block sum.
__global__ __launch_bounds__(256) void k_scan1(const int* __restrict__ cnt,
                                               int* __restrict__ part,
                                               int* __restrict__ bsums) {
    __shared__ int s[256];
    int tid = threadIdx.x;
    int i4 = blockIdx.x * (CHUNK / 4) + tid;             // int4 index
    int4 v = reinterpret_cast<const int4*>(cnt)[i4];
    int tsum = v.x + v.y + v.z + v.w;
    s[tid] = tsum;
    __syncthreads();
    for (int off = 1; off < 256; off <<= 1) {
        int t = 0;
        if (tid >= off) t = s[tid - off];
        __syncthreads();
        if (tid >= off) s[tid] += t;
        __syncthreads();
    }
    int excl = tid ? s[tid - 1] : 0;
    if (tid == 255) bsums[blockIdx.x] = s[255];
    int4 o;
    o.x = excl;
    o.y = o.x + v.x;
    o.z = o.y + v.y;
    o.w = o.z + v.z;
    reinterpret_cast<int4*>(part)[i4] = o;
}

// Exclusive scan of the (<=256) block sums, in place.
__global__ __launch_bounds__(256) void k_scan2(int* __restrict__ bsums, int nb) {
    __shared__ int s[256];
    int tid = threadIdx.x;
    int v = (tid < nb) ? bsums[tid] : 0;
    s[tid] = v;
    __syncthreads();
    for (int off = 1; off < 256; off <<= 1) {
        int t = 0;
        if (tid >= off) t = s[tid - off];
        __syncthreads();
        if (tid >= off) s[tid] += t;
        __syncthreads();
    }
    if (tid < nb) bsums[tid] = tid ? s[tid - 1] : 0;
}

// Add block offsets; also produce deg_inv = 1/max(deg,1).
__global__ __launch_bounds__(256) void k_scan3(int* __restrict__ row_ptr,
                                               const int* __restrict__ bsums,
                                               const int* __restrict__ cnt,
                                               float* __restrict__ deg_inv, int n) {
    int i = blockIdx.x * 256 + threadIdx.x;
    if (i < NPAD) {
        row_ptr[i] += bsums[i >> 10];
        if (i < n) {
            int dg = cnt[i];
            deg_inv[i] = 1.0f / (float)(dg > 1 ? dg : 1);
        }
    }
}

__global__ __launch_bounds__(256) void k_scatter(const int* __restrict__ src,
                                                 const int* __restrict__ dst,
                                                 const int* __restrict__ row_ptr,
                                                 int* __restrict__ fill,
                                                 int* __restrict__ col, int E) {
    int e = blockIdx.x * 256 + threadIdx.x;
    if (e < E) {
        int d = dst[e];
        int pos = row_ptr[d] + atomicAdd(&fill[d], 1);
        col[pos] = src[e];
    }
}

// ---------------- mean aggregation: one wave per node, lane = feature ----------------

__global__ __launch_bounds__(256) void k_agg(const float* __restrict__ xin,
                                             float* __restrict__ agg,
                                             const int* __restrict__ row_ptr,
                                             const int* __restrict__ col,
                                             const float* __restrict__ deg_inv, int n) {
    int node = blockIdx.x * 4 + (threadIdx.x >> 6);
    int lane = threadIdx.x & 63;
    if (node >= n) return;
    int beg = row_ptr[node], end = row_ptr[node + 1];
    float acc = 0.f;
    int e = beg;
    for (; e + 4 <= end; e += 4) {
        int s0 = col[e], s1 = col[e + 1], s2 = col[e + 2], s3 = col[e + 3];
        float a = xin[s0 * D + lane];
        float b = xin[s1 * D + lane];
        float c = xin[s2 * D + lane];
        float d = xin[s3 * D + lane];
        acc += a + b + c + d;
    }
    for (; e < end; ++e) acc += xin[col[e] * D + lane];
    agg[node * D + lane] = acc * deg_inv[node];
}

// ---------------- dense node-wise linear ----------------
// out[n] = (RELU?)( agg[n] @ Wl^T + bl  (+ xin[n] @ Wr^T if TWO) )
// Safe when out aliases agg or xin: rows are staged to LDS before writing.

template <int DOUT, bool RELU, bool TWO>
__global__ __launch_bounds__(256) void k_linear(const float* __restrict__ agg,
                                                const float* __restrict__ xin,
                                                const float* __restrict__ Wl,
                                                const float* __restrict__ bl,
                                                const float* __restrict__ Wr,
                                                float* __restrict__ out, int n) {
    constexpr int NPB = 256 / DOUT;
    __shared__ float sWl[DOUT * 65];
    __shared__ float sWr[TWO ? DOUT * 65 : 1];
    __shared__ float sA[NPB][D];
    __shared__ float sX[TWO ? NPB : 1][D];

    int tid = threadIdx.x;
    for (int i = tid; i < DOUT * D; i += 256) {
        int o = i >> 6, k = i & 63;
        sWl[o * 65 + k] = Wl[i];
        if (TWO) sWr[o * 65 + k] = Wr[i];
    }
    int node0 = blockIdx.x * NPB;
    for (int i = tid; i < NPB * D; i += 256) {
        int nl = i >> 6, k = i & 63;
        int nn = node0 + nl;
        float a = 0.f, xv = 0.f;
        if (nn < n) {
            a = agg[nn * D + k];
            if (TWO) xv = xin[nn * D + k];
        }
        sA[nl][k] = a;
        if (TWO) sX[nl][k] = xv;
    }
    __syncthreads();

    int o = tid % DOUT;
    int nl = tid / DOUT;
    int nn = node0 + nl;
    if (nn >= n) return;
    float acc = bl[o];
#pragma unroll
    for (int k = 0; k < D; ++k) {
        acc += sA[nl][k] * sWl[o * 65 + k];
        if (TWO) acc += sX[nl][k] * sWr[o * 65 + k];
    }
    if (RELU) acc = fmaxf(acc, 0.f);
    out[nn * DOUT + o] = acc;
}

// ---------------- launch ----------------

extern "C" void kernel_launch(void* const* d_in, const int* in_sizes, int n_in,
                              void* d_out, int out_size, void* d_ws, size_t ws_size,
                              hipStream_t stream) {
    const float* x   = (const float*)d_in[0];
    const int*   ei  = (const int*)d_in[1];
    const int    E   = in_sizes[1] / 2;
    const int*   src = ei;
    const int*   dst = ei + E;
    const float* W1l = (const float*)d_in[2];
    const float* b1l = (const float*)d_in[3];
    const float* W1r = (const float*)d_in[4];
    const float* W2l = (const float*)d_in[5];
    const float* b2l = (const float*)d_in[6];
    const float* W2r = (const float*)d_in[7];
    const float* W3l = (const float*)d_in[8];
    const float* b3l = (const float*)d_in[9];
    const float* W3r = (const float*)d_in[10];
    const float* Wfc = (const float*)d_in[11];
    const float* bfc = (const float*)d_in[12];
    float* out = (float*)d_out;

    char* p = (char*)d_ws;
    size_t off = 0;
    auto take = [&](size_t bytes) -> void* {
        void* r = p + off;
        off = (off + bytes + 255) & ~(size_t)255;
        return r;
    };
    float* A       = (float*)take((size_t)N_NODES * D * 4);
    float* H       = (float*)take((size_t)N_NODES * D * 4);
    float* deg_inv = (float*)take((size_t)N_NODES * 4);
    int*   cnt     = (int*)take((size_t)NPAD * 4);
    int*   fill    = (int*)take((size_t)N_NODES * 4);
    int*   row_ptr = (int*)take((size_t)(NPAD + 16) * 4);
    int*   bsums   = (int*)take(256 * 4);
    int*   col     = (int*)take((size_t)E * 4);

    hipMemsetAsync(cnt, 0, (size_t)NPAD * 4, stream);
    hipMemsetAsync(fill, 0, (size_t)N_NODES * 4, stream);

    int ge = (E + 255) / 256;
    k_count<<<ge, 256, 0, stream>>>(dst, cnt, E);
    int nb = NPAD / CHUNK;  // 98
    k_scan1<<<nb, 256, 0, stream>>>(cnt, row_ptr, bsums);
    k_scan2<<<1, 256, 0, stream>>>(bsums, nb);
    k_scan3<<<(NPAD + 255) / 256, 256, 0, stream>>>(row_ptr, bsums, cnt, deg_inv, N_NODES);
    k_scatter<<<ge, 256, 0, stream>>>(src, dst, row_ptr, fill, col, E);

    int ga = (N_NODES + 3) / 4;  // 4 nodes (waves) per block

    // layer 1: x -> H
    k_agg<<<ga, 256, 0, stream>>>(x, A, row_ptr, col, deg_inv, N_NODES);
    k_linear<64, true, true><<<ga, 256, 0, stream>>>(A, x, W1l, b1l, W1r, H, N_NODES);
    // layer 2: H -> H (in place; rows staged in LDS)
    k_agg<<<ga, 256, 0, stream>>>(H, A, row_ptr, col, deg_inv, N_NODES);
    k_linear<64, true, true><<<ga, 256, 0, stream>>>(A, H, W2l, b2l, W2r, H, N_NODES);
    // layer 3: H -> H
    k_agg<<<ga, 256, 0, stream>>>(H, A, row_ptr, col, deg_inv, N_NODES);
    k_linear<64, true, true><<<ga, 256, 0, stream>>>(A, H, W3l, b3l, W3r, H, N_NODES);
    // final fc: H -> out
    k_linear<32, false, false><<<(N_NODES + 7) / 8, 256, 0, stream>>>(
        H, nullptr, Wfc, bfc, nullptr, out, N_NODES);
}

// Round 2
// 533.325 us; speedup vs baseline: 1.3209x; 1.3209x over previous
//
#include <hip/hip_runtime.h>

#define N_NODES 100000
#define D 64
#define NPAD 100352   // N_NODES rounded up to multiple of 1024
#define CHUNK 1024

__device__ __forceinline__ float bcastf(float v, int l) {
    union { float f; int i; } u;
    u.f = v;
    u.i = __builtin_amdgcn_readlane(u.i, l);
    return u.f;
}

// ---------------- CSR build ----------------

// count + rank: rank[e] = position of edge e within its dst group
__global__ __launch_bounds__(256) void k_count(const int* __restrict__ dst,
                                               int* __restrict__ cnt,
                                               int* __restrict__ rank, int E) {
    int t = blockIdx.x * 1024 + threadIdx.x;
    int e0 = t, e1 = t + 256, e2 = t + 512, e3 = t + 768;
    int d0 = 0, d1 = 0, d2 = 0, d3 = 0;
    if (e0 < E) d0 = dst[e0];
    if (e1 < E) d1 = dst[e1];
    if (e2 < E) d2 = dst[e2];
    if (e3 < E) d3 = dst[e3];
    int r0 = 0, r1 = 0, r2 = 0, r3 = 0;
    if (e0 < E) r0 = atomicAdd(&cnt[d0], 1);
    if (e1 < E) r1 = atomicAdd(&cnt[d1], 1);
    if (e2 < E) r2 = atomicAdd(&cnt[d2], 1);
    if (e3 < E) r3 = atomicAdd(&cnt[d3], 1);
    if (e0 < E) rank[e0] = r0;
    if (e1 < E) rank[e1] = r1;
    if (e2 < E) rank[e2] = r2;
    if (e3 < E) rank[e3] = r3;
}

// Per-block exclusive scan over 1024 ints; writes partial scan + block sum.
__global__ __launch_bounds__(256) void k_scan1(const int* __restrict__ cnt,
                                               int* __restrict__ part,
                                               int* __restrict__ bsums) {
    __shared__ int s[256];
    int tid = threadIdx.x;
    int i4 = blockIdx.x * (CHUNK / 4) + tid;
    int4 v = reinterpret_cast<const int4*>(cnt)[i4];
    int tsum = v.x + v.y + v.z + v.w;
    s[tid] = tsum;
    __syncthreads();
    for (int off = 1; off < 256; off <<= 1) {
        int t = 0;
        if (tid >= off) t = s[tid - off];
        __syncthreads();
        if (tid >= off) s[tid] += t;
        __syncthreads();
    }
    int excl = tid ? s[tid - 1] : 0;
    if (tid == 255) bsums[blockIdx.x] = s[255];
    int4 o;
    o.x = excl;
    o.y = o.x + v.x;
    o.z = o.y + v.y;
    o.w = o.z + v.z;
    reinterpret_cast<int4*>(part)[i4] = o;
}

__global__ __launch_bounds__(256) void k_scan2(int* __restrict__ bsums, int nb) {
    __shared__ int s[256];
    int tid = threadIdx.x;
    int v = (tid < nb) ? bsums[tid] : 0;
    s[tid] = v;
    __syncthreads();
    for (int off = 1; off < 256; off <<= 1) {
        int t = 0;
        if (tid >= off) t = s[tid - off];
        __syncthreads();
        if (tid >= off) s[tid] += t;
        __syncthreads();
    }
    if (tid < nb) bsums[tid] = tid ? s[tid - 1] : 0;
}

__global__ __launch_bounds__(256) void k_scan3(int* __restrict__ row_ptr,
                                               const int* __restrict__ bsums,
                                               const int* __restrict__ cnt,
                                               float* __restrict__ deg_inv, int n) {
    int i = blockIdx.x * 256 + threadIdx.x;
    if (i < NPAD) {
        row_ptr[i] += bsums[i >> 10];
        if (i < n) {
            int dg = cnt[i];
            deg_inv[i] = 1.0f / (float)(dg > 1 ? dg : 1);
        }
    }
}

// atomic-free scatter: pos = row_ptr[d] + rank[e]
__global__ __launch_bounds__(256) void k_scatter(const int* __restrict__ src,
                                                 const int* __restrict__ dst,
                                                 const int* __restrict__ row_ptr,
                                                 const int* __restrict__ rank,
                                                 int* __restrict__ col, int E) {
    int t = blockIdx.x * 1024 + threadIdx.x;
    int e0 = t, e1 = t + 256, e2 = t + 512, e3 = t + 768;
    int d0, d1, d2, d3, r0, r1, r2, r3, s0, s1, s2, s3;
    if (e0 < E) { d0 = dst[e0]; r0 = rank[e0]; s0 = src[e0]; }
    if (e1 < E) { d1 = dst[e1]; r1 = rank[e1]; s1 = src[e1]; }
    if (e2 < E) { d2 = dst[e2]; r2 = rank[e2]; s2 = src[e2]; }
    if (e3 < E) { d3 = dst[e3]; r3 = rank[e3]; s3 = src[e3]; }
    int p0, p1, p2, p3;
    if (e0 < E) p0 = row_ptr[d0];
    if (e1 < E) p1 = row_ptr[d1];
    if (e2 < E) p2 = row_ptr[d2];
    if (e3 < E) p3 = row_ptr[d3];
    if (e0 < E) col[p0 + r0] = s0;
    if (e1 < E) col[p1 + r1] = s1;
    if (e2 < E) col[p2 + r2] = s2;
    if (e3 < E) col[p3 + r3] = s3;
}

// ---------------- mean aggregation: one wave per node, lane = feature ----------------

__global__ __launch_bounds__(256) void k_agg(const float* __restrict__ xin,
                                             float* __restrict__ agg,
                                             const int* __restrict__ row_ptr,
                                             const int* __restrict__ col,
                                             const float* __restrict__ deg_inv, int n) {
    int node = blockIdx.x * 4 + (threadIdx.x >> 6);
    int lane = threadIdx.x & 63;
    if (node >= n) return;
    int beg = row_ptr[node], end = row_ptr[node + 1];
    int deg = end - beg;
    int dc = deg < 64 ? deg : 64;
    int myc = 0;
    if (lane < dc) myc = col[beg + lane];
    float acc = 0.f;
    int j = 0;
    for (; j + 8 <= dc; j += 8) {
        int s0 = __shfl(myc, j + 0), s1 = __shfl(myc, j + 1);
        int s2 = __shfl(myc, j + 2), s3 = __shfl(myc, j + 3);
        int s4 = __shfl(myc, j + 4), s5 = __shfl(myc, j + 5);
        int s6 = __shfl(myc, j + 6), s7 = __shfl(myc, j + 7);
        float a0 = xin[s0 * D + lane], a1 = xin[s1 * D + lane];
        float a2 = xin[s2 * D + lane], a3 = xin[s3 * D + lane];
        float a4 = xin[s4 * D + lane], a5 = xin[s5 * D + lane];
        float a6 = xin[s6 * D + lane], a7 = xin[s7 * D + lane];
        acc += ((a0 + a1) + (a2 + a3)) + ((a4 + a5) + (a6 + a7));
    }
    for (; j < dc; ++j) acc += xin[__shfl(myc, j) * D + lane];
    for (int e = beg + 64; e < end; ++e) acc += xin[col[e] * D + lane];  // deg>64 tail
    agg[node * D + lane] = acc * deg_inv[node];
}

// ---------------- LDS-free linear: weights in VGPRs, readlane broadcast ----------------
// out[n] = relu( A[n] @ Wl^T + bl + X[n] @ Wr^T ).  In-place (out==X) safe:
// each lane only touches its own node's row.

__global__ __launch_bounds__(256) void k_lin64(const float* __restrict__ A,
                                               const float* __restrict__ X,
                                               const float* __restrict__ Wl,
                                               const float* __restrict__ bl,
                                               const float* __restrict__ Wr,
                                               float* __restrict__ out, int n) {
    int lane = threadIdx.x & 63;
    int wid = (blockIdx.x * 256 + threadIdx.x) >> 6;
    int nw = gridDim.x * 4;
    float wl[64], wr[64];
    const float4* Wl4 = (const float4*)Wl;
    const float4* Wr4 = (const float4*)Wr;
#pragma unroll
    for (int j = 0; j < 16; ++j) {
        float4 a = Wl4[lane * 16 + j];
        wl[4 * j] = a.x; wl[4 * j + 1] = a.y; wl[4 * j + 2] = a.z; wl[4 * j + 3] = a.w;
        float4 b = Wr4[lane * 16 + j];
        wr[4 * j] = b.x; wr[4 * j + 1] = b.y; wr[4 * j + 2] = b.z; wr[4 * j + 3] = b.w;
    }
    float bv = bl[lane];
    for (int node = wid; node < n; node += nw) {
        float av = A[node * D + lane];
        float xv = X[node * D + lane];
        float o = bv;
#pragma unroll
        for (int k = 0; k < 64; ++k) {
            o += bcastf(av, k) * wl[k];
            o += bcastf(xv, k) * wr[k];
        }
        out[node * D + lane] = fmaxf(o, 0.f);
    }
}

// final fc: [N,64] @ [32,64]^T + b. All 64 lanes compute (lanes 32-63 duplicate);
// lanes 0-31 store.
__global__ __launch_bounds__(256) void k_fc32(const float* __restrict__ H,
                                              const float* __restrict__ Wfc,
                                              const float* __restrict__ bfc,
                                              float* __restrict__ out, int n) {
    int lane = threadIdx.x & 63;
    int o = lane & 31;
    int wid = (blockIdx.x * 256 + threadIdx.x) >> 6;
    int nw = gridDim.x * 4;
    float w[64];
    const float4* W4 = (const float4*)Wfc;
#pragma unroll
    for (int j = 0; j < 16; ++j) {
        float4 a = W4[o * 16 + j];
        w[4 * j] = a.x; w[4 * j + 1] = a.y; w[4 * j + 2] = a.z; w[4 * j + 3] = a.w;
    }
    float bv = bfc[o];
    for (int node = wid; node < n; node += nw) {
        float hv = H[node * D + lane];
        float acc = bv;
#pragma unroll
        for (int k = 0; k < 64; ++k) acc += bcastf(hv, k) * w[k];
        if (lane < 32) out[node * 32 + o] = acc;
    }
}

// ---------------- launch ----------------

extern "C" void kernel_launch(void* const* d_in, const int* in_sizes, int n_in,
                              void* d_out, int out_size, void* d_ws, size_t ws_size,
                              hipStream_t stream) {
    const float* x   = (const float*)d_in[0];
    const int*   ei  = (const int*)d_in[1];
    const int    E   = in_sizes[1] / 2;
    const int*   src = ei;
    const int*   dst = ei + E;
    const float* W1l = (const float*)d_in[2];
    const float* b1l = (const float*)d_in[3];
    const float* W1r = (const float*)d_in[4];
    const float* W2l = (const float*)d_in[5];
    const float* b2l = (const float*)d_in[6];
    const float* W2r = (const float*)d_in[7];
    const float* W3l = (const float*)d_in[8];
    const float* b3l = (const float*)d_in[9];
    const float* W3r = (const float*)d_in[10];
    const float* Wfc = (const float*)d_in[11];
    const float* bfc = (const float*)d_in[12];
    float* out = (float*)d_out;

    char* p = (char*)d_ws;
    size_t off = 0;
    auto take = [&](size_t bytes) -> void* {
        void* r = p + off;
        off = (off + bytes + 255) & ~(size_t)255;
        return r;
    };
    float* A       = (float*)take((size_t)N_NODES * D * 4);
    float* H       = (float*)take((size_t)N_NODES * D * 4);
    float* deg_inv = (float*)take((size_t)N_NODES * 4);
    int*   cnt     = (int*)take((size_t)NPAD * 4);
    int*   row_ptr = (int*)take((size_t)(NPAD + 16) * 4);
    int*   bsums   = (int*)take(256 * 4);
    int*   rank    = (int*)take((size_t)E * 4);
    int*   col     = (int*)take((size_t)E * 4);

    hipMemsetAsync(cnt, 0, (size_t)NPAD * 4, stream);

    int ge4 = (E + 1023) / 1024;
    k_count<<<ge4, 256, 0, stream>>>(dst, cnt, rank, E);
    int nb = NPAD / CHUNK;  // 98
    k_scan1<<<nb, 256, 0, stream>>>(cnt, row_ptr, bsums);
    k_scan2<<<1, 256, 0, stream>>>(bsums, nb);
    k_scan3<<<(NPAD + 255) / 256, 256, 0, stream>>>(row_ptr, bsums, cnt, deg_inv, N_NODES);
    k_scatter<<<ge4, 256, 0, stream>>>(src, dst, row_ptr, rank, col, E);

    int ga = (N_NODES + 3) / 4;     // wave per node
    int gl = 2048;                  // grid-stride for linear kernels

    // layer 1: x -> H
    k_agg<<<ga, 256, 0, stream>>>(x, A, row_ptr, col, deg_inv, N_NODES);
    k_lin64<<<gl, 256, 0, stream>>>(A, x, W1l, b1l, W1r, H, N_NODES);
    // layer 2: H -> H (in place, lane-private rows)
    k_agg<<<ga, 256, 0, stream>>>(H, A, row_ptr, col, deg_inv, N_NODES);
    k_lin64<<<gl, 256, 0, stream>>>(A, H, W2l, b2l, W2r, H, N_NODES);
    // layer 3: H -> H
    k_agg<<<ga, 256, 0, stream>>>(H, A, row_ptr, col, deg_inv, N_NODES);
    k_lin64<<<gl, 256, 0, stream>>>(A, H, W3l, b3l, W3r, H, N_NODES);
    // final fc
    k_fc32<<<gl, 256, 0, stream>>>(H, Wfc, bfc, out, N_NODES);
}

// Round 3
// 459.019 us; speedup vs baseline: 1.5347x; 1.1619x over previous
//
#include <hip/hip_runtime.h>

#define N_NODES 100000
#define D 64
#define NPAD 100352   // N_NODES rounded up to multiple of 1024
#define CHUNK 1024

// ---------------- CSR build ----------------

// count + rank: rank[e] = position of edge e within its dst group
__global__ __launch_bounds__(256) void k_count(const int* __restrict__ dst,
                                               int* __restrict__ cnt,
                                               int* __restrict__ rank, int E) {
    int t = blockIdx.x * 1024 + threadIdx.x;
    int e0 = t, e1 = t + 256, e2 = t + 512, e3 = t + 768;
    int d0 = 0, d1 = 0, d2 = 0, d3 = 0;
    if (e0 < E) d0 = dst[e0];
    if (e1 < E) d1 = dst[e1];
    if (e2 < E) d2 = dst[e2];
    if (e3 < E) d3 = dst[e3];
    int r0 = 0, r1 = 0, r2 = 0, r3 = 0;
    if (e0 < E) r0 = atomicAdd(&cnt[d0], 1);
    if (e1 < E) r1 = atomicAdd(&cnt[d1], 1);
    if (e2 < E) r2 = atomicAdd(&cnt[d2], 1);
    if (e3 < E) r3 = atomicAdd(&cnt[d3], 1);
    if (e0 < E) rank[e0] = r0;
    if (e1 < E) rank[e1] = r1;
    if (e2 < E) rank[e2] = r2;
    if (e3 < E) rank[e3] = r3;
}

// Per-block exclusive scan over 1024 ints; writes partial scan + block sum.
__global__ __launch_bounds__(256) void k_scan1(const int* __restrict__ cnt,
                                               int* __restrict__ part,
                                               int* __restrict__ bsums) {
    __shared__ int s[256];
    int tid = threadIdx.x;
    int i4 = blockIdx.x * (CHUNK / 4) + tid;
    int4 v = reinterpret_cast<const int4*>(cnt)[i4];
    int tsum = v.x + v.y + v.z + v.w;
    s[tid] = tsum;
    __syncthreads();
    for (int off = 1; off < 256; off <<= 1) {
        int t = 0;
        if (tid >= off) t = s[tid - off];
        __syncthreads();
        if (tid >= off) s[tid] += t;
        __syncthreads();
    }
    int excl = tid ? s[tid - 1] : 0;
    if (tid == 255) bsums[blockIdx.x] = s[255];
    int4 o;
    o.x = excl;
    o.y = o.x + v.x;
    o.z = o.y + v.y;
    o.w = o.z + v.z;
    reinterpret_cast<int4*>(part)[i4] = o;
}

__global__ __launch_bounds__(256) void k_scan2(int* __restrict__ bsums, int nb) {
    __shared__ int s[256];
    int tid = threadIdx.x;
    int v = (tid < nb) ? bsums[tid] : 0;
    s[tid] = v;
    __syncthreads();
    for (int off = 1; off < 256; off <<= 1) {
        int t = 0;
        if (tid >= off) t = s[tid - off];
        __syncthreads();
        if (tid >= off) s[tid] += t;
        __syncthreads();
    }
    if (tid < nb) bsums[tid] = tid ? s[tid - 1] : 0;
}

__global__ __launch_bounds__(256) void k_scan3(int* __restrict__ row_ptr,
                                               const int* __restrict__ bsums,
                                               const int* __restrict__ cnt,
                                               float* __restrict__ deg_inv, int n) {
    int i = blockIdx.x * 256 + threadIdx.x;
    if (i < NPAD) {
        row_ptr[i] += bsums[i >> 10];
        if (i < n) {
            int dg = cnt[i];
            deg_inv[i] = 1.0f / (float)(dg > 1 ? dg : 1);
        }
    }
}

// atomic-free scatter: pos = row_ptr[d] + rank[e]
__global__ __launch_bounds__(256) void k_scatter(const int* __restrict__ src,
                                                 const int* __restrict__ dst,
                                                 const int* __restrict__ row_ptr,
                                                 const int* __restrict__ rank,
                                                 int* __restrict__ col, int E) {
    int t = blockIdx.x * 1024 + threadIdx.x;
    int e0 = t, e1 = t + 256, e2 = t + 512, e3 = t + 768;
    int d0, d1, d2, d3, r0, r1, r2, r3, s0, s1, s2, s3;
    if (e0 < E) { d0 = dst[e0]; r0 = rank[e0]; s0 = src[e0]; }
    if (e1 < E) { d1 = dst[e1]; r1 = rank[e1]; s1 = src[e1]; }
    if (e2 < E) { d2 = dst[e2]; r2 = rank[e2]; s2 = src[e2]; }
    if (e3 < E) { d3 = dst[e3]; r3 = rank[e3]; s3 = src[e3]; }
    int p0, p1, p2, p3;
    if (e0 < E) p0 = row_ptr[d0];
    if (e1 < E) p1 = row_ptr[d1];
    if (e2 < E) p2 = row_ptr[d2];
    if (e3 < E) p3 = row_ptr[d3];
    if (e0 < E) col[p0 + r0] = s0;
    if (e1 < E) col[p1 + r1] = s1;
    if (e2 < E) col[p2 + r2] = s2;
    if (e3 < E) col[p3 + r3] = s3;
}

// ---------------- mean aggregation: one wave per node, lane = feature ----------------

__global__ __launch_bounds__(256) void k_agg(const float* __restrict__ xin,
                                             float* __restrict__ agg,
                                             const int* __restrict__ row_ptr,
                                             const int* __restrict__ col,
                                             const float* __restrict__ deg_inv, int n) {
    int node = blockIdx.x * 4 + (threadIdx.x >> 6);
    int lane = threadIdx.x & 63;
    if (node >= n) return;
    int beg = row_ptr[node], end = row_ptr[node + 1];
    int deg = end - beg;
    int dc = deg < 64 ? deg : 64;
    int myc = 0;
    if (lane < dc) myc = col[beg + lane];
    float acc = 0.f;
    int j = 0;
    for (; j + 8 <= dc; j += 8) {
        int s0 = __shfl(myc, j + 0), s1 = __shfl(myc, j + 1);
        int s2 = __shfl(myc, j + 2), s3 = __shfl(myc, j + 3);
        int s4 = __shfl(myc, j + 4), s5 = __shfl(myc, j + 5);
        int s6 = __shfl(myc, j + 6), s7 = __shfl(myc, j + 7);
        float a0 = xin[s0 * D + lane], a1 = xin[s1 * D + lane];
        float a2 = xin[s2 * D + lane], a3 = xin[s3 * D + lane];
        float a4 = xin[s4 * D + lane], a5 = xin[s5 * D + lane];
        float a6 = xin[s6 * D + lane], a7 = xin[s7 * D + lane];
        acc += ((a0 + a1) + (a2 + a3)) + ((a4 + a5) + (a6 + a7));
    }
    for (; j < dc; ++j) acc += xin[__shfl(myc, j) * D + lane];
    for (int e = beg + 64; e < end; ++e) acc += xin[col[e] * D + lane];  // deg>64 tail
    agg[node * D + lane] = acc * deg_inv[node];
}

// ---------------- weight prep: Wt[k][o] = W[o][k], Wl/Wr stacked along k ----------------

__global__ __launch_bounds__(256) void k_prep(const float* __restrict__ Wl1, const float* __restrict__ Wr1,
                                              const float* __restrict__ Wl2, const float* __restrict__ Wr2,
                                              const float* __restrict__ Wl3, const float* __restrict__ Wr3,
                                              const float* __restrict__ Wfc,
                                              float* __restrict__ Wt1, float* __restrict__ Wt2,
                                              float* __restrict__ Wt3, float* __restrict__ Wtfc) {
    int t = blockIdx.x * 256 + threadIdx.x;
    if (t < 4096) {
        int k = t >> 6, o = t & 63;
        Wt1[k * 64 + o] = Wl1[o * 64 + k];
        Wt1[(k + 64) * 64 + o] = Wr1[o * 64 + k];
        Wt2[k * 64 + o] = Wl2[o * 64 + k];
        Wt2[(k + 64) * 64 + o] = Wr2[o * 64 + k];
        Wt3[k * 64 + o] = Wl3[o * 64 + k];
        Wt3[(k + 64) * 64 + o] = Wr3[o * 64 + k];
        if (o < 32) Wtfc[k * 32 + o] = Wfc[o * 64 + k];
    }
}

// ---------------- fused linear as register-tiled GEMM ----------------
// out[n][DOUT] = (RELU?)( [A[n] | X[n]] @ Wt + bias )
// lane = node, acc[DOUT] per lane; weights via wave-uniform loads -> s_load;
// activations via LDS transpose, stride-1 reads (conflict-free).
// In-place out==X safe: block writes only its own rows, after last chunk staged.

template <int DOUT, bool RELU, bool TWO>
__global__ __launch_bounds__(128) void k_gemm(const float* __restrict__ A,
                                              const float* __restrict__ X,
                                              const float* __restrict__ Wt,
                                              const float* __restrict__ bias,
                                              float* __restrict__ out, int n) {
    constexpr int NCH = TWO ? 4 : 2;   // K chunks of 32
    __shared__ float Xt[32][129];
    int tid = threadIdx.x;             // 0..127, per-thread node
    int mynode = blockIdx.x * 128 + tid;
    bool act = mynode < n;

    float acc[DOUT];
#pragma unroll
    for (int o = 0; o < DOUT; ++o) acc[o] = bias[o];   // uniform -> s_load

    for (int ch = 0; ch < NCH; ++ch) {
        const float* srcp = (TWO && ch >= 2) ? X : A;
        int kbase = (ch & (TWO ? 1 : 3)) * 32;
        __syncthreads();
        if (act) {
            const float4* rp = (const float4*)(srcp + (size_t)mynode * D + kbase);
#pragma unroll
            for (int j = 0; j < 8; ++j) {
                float4 v = rp[j];
                Xt[j * 4 + 0][tid] = v.x;
                Xt[j * 4 + 1][tid] = v.y;
                Xt[j * 4 + 2][tid] = v.z;
                Xt[j * 4 + 3][tid] = v.w;
            }
        }
        __syncthreads();
        const float* wrow = Wt + (size_t)ch * 32 * DOUT;
#pragma unroll 2
        for (int k = 0; k < 32; ++k) {
            float xv = Xt[k][tid];
#pragma unroll
            for (int o = 0; o < DOUT; ++o)
                acc[o] = fmaf(xv, wrow[k * DOUT + o], acc[o]);  // wrow uniform -> s_load
        }
    }
    if (act) {
        float4* op = (float4*)(out + (size_t)mynode * DOUT);
#pragma unroll
        for (int j = 0; j < DOUT / 4; ++j) {
            float4 v;
            v.x = RELU ? fmaxf(acc[4 * j + 0], 0.f) : acc[4 * j + 0];
            v.y = RELU ? fmaxf(acc[4 * j + 1], 0.f) : acc[4 * j + 1];
            v.z = RELU ? fmaxf(acc[4 * j + 2], 0.f) : acc[4 * j + 2];
            v.w = RELU ? fmaxf(acc[4 * j + 3], 0.f) : acc[4 * j + 3];
            op[j] = v;
        }
    }
}

// ---------------- launch ----------------

extern "C" void kernel_launch(void* const* d_in, const int* in_sizes, int n_in,
                              void* d_out, int out_size, void* d_ws, size_t ws_size,
                              hipStream_t stream) {
    const float* x   = (const float*)d_in[0];
    const int*   ei  = (const int*)d_in[1];
    const int    E   = in_sizes[1] / 2;
    const int*   src = ei;
    const int*   dst = ei + E;
    const float* W1l = (const float*)d_in[2];
    const float* b1l = (const float*)d_in[3];
    const float* W1r = (const float*)d_in[4];
    const float* W2l = (const float*)d_in[5];
    const float* b2l = (const float*)d_in[6];
    const float* W2r = (const float*)d_in[7];
    const float* W3l = (const float*)d_in[8];
    const float* b3l = (const float*)d_in[9];
    const float* W3r = (const float*)d_in[10];
    const float* Wfc = (const float*)d_in[11];
    const float* bfc = (const float*)d_in[12];
    float* out = (float*)d_out;

    char* p = (char*)d_ws;
    size_t off = 0;
    auto take = [&](size_t bytes) -> void* {
        void* r = p + off;
        off = (off + bytes + 255) & ~(size_t)255;
        return r;
    };
    float* A       = (float*)take((size_t)N_NODES * D * 4);
    float* H       = (float*)take((size_t)N_NODES * D * 4);
    float* deg_inv = (float*)take((size_t)N_NODES * 4);
    int*   cnt     = (int*)take((size_t)NPAD * 4);
    int*   row_ptr = (int*)take((size_t)(NPAD + 16) * 4);
    int*   bsums   = (int*)take(256 * 4);
    int*   rank    = (int*)take((size_t)E * 4);
    int*   col     = (int*)take((size_t)E * 4);
    float* Wt1     = (float*)take(128 * 64 * 4);
    float* Wt2     = (float*)take(128 * 64 * 4);
    float* Wt3     = (float*)take(128 * 64 * 4);
    float* Wtfc    = (float*)take(64 * 32 * 4);

    hipMemsetAsync(cnt, 0, (size_t)NPAD * 4, stream);

    k_prep<<<16, 256, 0, stream>>>(W1l, W1r, W2l, W2r, W3l, W3r, Wfc, Wt1, Wt2, Wt3, Wtfc);

    int ge4 = (E + 1023) / 1024;
    k_count<<<ge4, 256, 0, stream>>>(dst, cnt, rank, E);
    int nb = NPAD / CHUNK;  // 98
    k_scan1<<<nb, 256, 0, stream>>>(cnt, row_ptr, bsums);
    k_scan2<<<1, 256, 0, stream>>>(bsums, nb);
    k_scan3<<<(NPAD + 255) / 256, 256, 0, stream>>>(row_ptr, bsums, cnt, deg_inv, N_NODES);
    k_scatter<<<ge4, 256, 0, stream>>>(src, dst, row_ptr, rank, col, E);

    int ga = (N_NODES + 3) / 4;        // wave per node (agg)
    int gg = (N_NODES + 127) / 128;    // 782 blocks (gemm)

    // layer 1: x -> H
    k_agg<<<ga, 256, 0, stream>>>(x, A, row_ptr, col, deg_inv, N_NODES);
    k_gemm<64, true, true><<<gg, 128, 0, stream>>>(A, x, Wt1, b1l, H, N_NODES);
    // layer 2: H -> H (in place)
    k_agg<<<ga, 256, 0, stream>>>(H, A, row_ptr, col, deg_inv, N_NODES);
    k_gemm<64, true, true><<<gg, 128, 0, stream>>>(A, H, Wt2, b2l, H, N_NODES);
    // layer 3: H -> H
    k_agg<<<ga, 256, 0, stream>>>(H, A, row_ptr, col, deg_inv, N_NODES);
    k_gemm<64, true, true><<<gg, 128, 0, stream>>>(A, H, Wt3, b3l, H, N_NODES);
    // final fc
    k_gemm<32, false, false><<<gg, 128, 0, stream>>>(H, nullptr, Wtfc, bfc, out, N_NODES);
}

// Round 4
// 435.476 us; speedup vs baseline: 1.6177x; 1.0541x over previous
//
#include <hip/hip_runtime.h>
#include <hip/hip_fp16.h>

#define N_NODES 100000
#define D 64
#define NPAD 100352   // N_NODES rounded up to multiple of 1024
#define CHUNK 1024

struct alignas(16) h8 { __half2 h[4]; };

// ---------------- x -> fp16 ----------------
__global__ __launch_bounds__(256) void k_cvt(const float4* __restrict__ x,
                                             uint2* __restrict__ y, int n4) {
    int i = blockIdx.x * 256 + threadIdx.x;
    if (i < n4) {
        float4 v = x[i];
        union { __half2 h[2]; uint2 u; } pk;
        pk.h[0] = __floats2half2_rn(v.x, v.y);
        pk.h[1] = __floats2half2_rn(v.z, v.w);
        y[i] = pk.u;
    }
}

// ---------------- CSR build ----------------

// count + rank (8 edges/thread for 8 outstanding return-atomics)
__global__ __launch_bounds__(256) void k_count(const int* __restrict__ dst,
                                               int* __restrict__ cnt,
                                               int* __restrict__ rank, int E) {
    int base = blockIdx.x * 2048 + threadIdx.x;
    int d[8], r[8];
    if (base + 1792 < E) {
#pragma unroll
        for (int i = 0; i < 8; ++i) d[i] = dst[base + i * 256];
#pragma unroll
        for (int i = 0; i < 8; ++i) r[i] = atomicAdd(&cnt[d[i]], 1);
#pragma unroll
        for (int i = 0; i < 8; ++i) rank[base + i * 256] = r[i];
    } else {
#pragma unroll
        for (int i = 0; i < 8; ++i) {
            int e = base + i * 256;
            if (e < E) rank[e] = atomicAdd(&cnt[dst[e]], 1);
        }
    }
}

// Per-block exclusive scan over 1024 ints; writes partial scan + block sum.
__global__ __launch_bounds__(256) void k_scan1(const int* __restrict__ cnt,
                                               int* __restrict__ part,
                                               int* __restrict__ bsums) {
    __shared__ int s[256];
    int tid = threadIdx.x;
    int i4 = blockIdx.x * (CHUNK / 4) + tid;
    int4 v = reinterpret_cast<const int4*>(cnt)[i4];
    int tsum = v.x + v.y + v.z + v.w;
    s[tid] = tsum;
    __syncthreads();
    for (int off = 1; off < 256; off <<= 1) {
        int t = 0;
        if (tid >= off) t = s[tid - off];
        __syncthreads();
        if (tid >= off) s[tid] += t;
        __syncthreads();
    }
    int excl = tid ? s[tid - 1] : 0;
    if (tid == 255) bsums[blockIdx.x] = s[255];
    int4 o;
    o.x = excl;
    o.y = o.x + v.x;
    o.z = o.y + v.y;
    o.w = o.z + v.z;
    reinterpret_cast<int4*>(part)[i4] = o;
}

__global__ __launch_bounds__(256) void k_scan2(int* __restrict__ bsums, int nb) {
    __shared__ int s[256];
    int tid = threadIdx.x;
    int v = (tid < nb) ? bsums[tid] : 0;
    s[tid] = v;
    __syncthreads();
    for (int off = 1; off < 256; off <<= 1) {
        int t = 0;
        if (tid >= off) t = s[tid - off];
        __syncthreads();
        if (tid >= off) s[tid] += t;
        __syncthreads();
    }
    if (tid < nb) bsums[tid] = tid ? s[tid - 1] : 0;
}

__global__ __launch_bounds__(256) void k_scan3(int* __restrict__ row_ptr,
                                               const int* __restrict__ bsums,
                                               const int* __restrict__ cnt,
                                               float* __restrict__ deg_inv, int n) {
    int i = blockIdx.x * 256 + threadIdx.x;
    if (i < NPAD) {
        row_ptr[i] += bsums[i >> 10];
        if (i < n) {
            int dg = cnt[i];
            deg_inv[i] = 1.0f / (float)(dg > 1 ? dg : 1);
        }
    }
}

// atomic-free scatter: pos = row_ptr[d] + rank[e]  (8 edges/thread)
__global__ __launch_bounds__(256) void k_scatter(const int* __restrict__ src,
                                                 const int* __restrict__ dst,
                                                 const int* __restrict__ row_ptr,
                                                 const int* __restrict__ rank,
                                                 int* __restrict__ col, int E) {
    int base = blockIdx.x * 2048 + threadIdx.x;
    int d[8], r[8], s[8], p[8];
    if (base + 1792 < E) {
#pragma unroll
        for (int i = 0; i < 8; ++i) {
            int e = base + i * 256;
            d[i] = dst[e]; r[i] = rank[e]; s[i] = src[e];
        }
#pragma unroll
        for (int i = 0; i < 8; ++i) p[i] = row_ptr[d[i]];
#pragma unroll
        for (int i = 0; i < 8; ++i) col[p[i] + r[i]] = s[i];
    } else {
#pragma unroll
        for (int i = 0; i < 8; ++i) {
            int e = base + i * 256;
            if (e < E) col[row_ptr[dst[e]] + rank[e]] = src[e];
        }
    }
}

// ---------------- mean aggregation (fp16 table): one wave per node ----------------

__global__ __launch_bounds__(256) void k_agg16(const __half* __restrict__ xin,
                                               __half* __restrict__ agg,
                                               const int* __restrict__ row_ptr,
                                               const int* __restrict__ col,
                                               const float* __restrict__ deg_inv, int n) {
    int node = blockIdx.x * 4 + (threadIdx.x >> 6);
    int lane = threadIdx.x & 63;
    if (node >= n) return;
    int beg = row_ptr[node], end = row_ptr[node + 1];
    int deg = end - beg;
    int dc = deg < 64 ? deg : 64;
    int myc = 0;
    if (lane < dc) myc = col[beg + lane];
    float acc = 0.f;
    int j = 0;
    for (; j + 8 <= dc; j += 8) {
        int s0 = __shfl(myc, j + 0), s1 = __shfl(myc, j + 1);
        int s2 = __shfl(myc, j + 2), s3 = __shfl(myc, j + 3);
        int s4 = __shfl(myc, j + 4), s5 = __shfl(myc, j + 5);
        int s6 = __shfl(myc, j + 6), s7 = __shfl(myc, j + 7);
        float a0 = __half2float(xin[s0 * D + lane]);
        float a1 = __half2float(xin[s1 * D + lane]);
        float a2 = __half2float(xin[s2 * D + lane]);
        float a3 = __half2float(xin[s3 * D + lane]);
        float a4 = __half2float(xin[s4 * D + lane]);
        float a5 = __half2float(xin[s5 * D + lane]);
        float a6 = __half2float(xin[s6 * D + lane]);
        float a7 = __half2float(xin[s7 * D + lane]);
        acc += ((a0 + a1) + (a2 + a3)) + ((a4 + a5) + (a6 + a7));
    }
    for (; j < dc; ++j) acc += __half2float(xin[__shfl(myc, j) * D + lane]);
    for (int e = beg + 64; e < end; ++e) acc += __half2float(xin[col[e] * D + lane]);
    agg[node * D + lane] = __float2half(acc * deg_inv[node]);
}

// ---------------- weight prep: Wt[k][o] = W[o][k], Wl/Wr stacked along k ----------------

__global__ __launch_bounds__(256) void k_prep(const float* __restrict__ Wl1, const float* __restrict__ Wr1,
                                              const float* __restrict__ Wl2, const float* __restrict__ Wr2,
                                              const float* __restrict__ Wl3, const float* __restrict__ Wr3,
                                              const float* __restrict__ Wfc,
                                              float* __restrict__ Wt1, float* __restrict__ Wt2,
                                              float* __restrict__ Wt3, float* __restrict__ Wtfc) {
    int t = blockIdx.x * 256 + threadIdx.x;
    if (t < 4096) {
        int k = t >> 6, o = t & 63;
        Wt1[k * 64 + o] = Wl1[o * 64 + k];
        Wt1[(k + 64) * 64 + o] = Wr1[o * 64 + k];
        Wt2[k * 64 + o] = Wl2[o * 64 + k];
        Wt2[(k + 64) * 64 + o] = Wr2[o * 64 + k];
        Wt3[k * 64 + o] = Wl3[o * 64 + k];
        Wt3[(k + 64) * 64 + o] = Wr3[o * 64 + k];
        if (o < 32) Wtfc[k * 32 + o] = Wfc[o * 64 + k];
    }
}

// ---------------- fused linear as register-tiled GEMM (fp16 activations) ----------------
// out[n][DOUT] = (RELU?)( [A[n] | X[n]] @ Wt + bias )
// lane = node, acc[DOUT] f32 per lane; weights via wave-uniform loads -> s_load;
// activations via LDS transpose (f32), stride-1 reads. In-place out==X safe.

template <int DOUT, bool RELU, bool TWO, bool HOUT>
__global__ __launch_bounds__(128) void k_gemm(const __half* __restrict__ A,
                                              const __half* __restrict__ X,
                                              const float* __restrict__ Wt,
                                              const float* __restrict__ bias,
                                              void* __restrict__ outp, int n) {
    constexpr int NCH = TWO ? 4 : 2;   // K chunks of 32
    __shared__ float Xt[32][129];
    int tid = threadIdx.x;             // 0..127, per-thread node
    int mynode = blockIdx.x * 128 + tid;
    bool act = mynode < n;

    float acc[DOUT];
#pragma unroll
    for (int o = 0; o < DOUT; ++o) acc[o] = bias[o];   // uniform -> s_load

    for (int ch = 0; ch < NCH; ++ch) {
        const __half* srcp = (TWO && ch >= 2) ? X : A;
        int kbase = (ch & (TWO ? 1 : 3)) * 32;
        __syncthreads();
        if (act) {
            const h8* rp = (const h8*)(srcp + (size_t)mynode * D + kbase);
#pragma unroll
            for (int j = 0; j < 4; ++j) {
                h8 v = rp[j];
#pragma unroll
                for (int q = 0; q < 4; ++q) {
                    float2 f = __half22float2(v.h[q]);
                    Xt[j * 8 + q * 2 + 0][tid] = f.x;
                    Xt[j * 8 + q * 2 + 1][tid] = f.y;
                }
            }
        }
        __syncthreads();
        const float* wrow = Wt + (size_t)ch * 32 * DOUT;
#pragma unroll 2
        for (int k = 0; k < 32; ++k) {
            float xv = Xt[k][tid];
#pragma unroll
            for (int o = 0; o < DOUT; ++o)
                acc[o] = fmaf(xv, wrow[k * DOUT + o], acc[o]);  // wrow uniform -> s_load
        }
    }
    if (act) {
        if (RELU) {
#pragma unroll
            for (int o = 0; o < DOUT; ++o) acc[o] = fmaxf(acc[o], 0.f);
        }
        if (HOUT) {
            h8* op = (h8*)((__half*)outp + (size_t)mynode * DOUT);
#pragma unroll
            for (int j = 0; j < DOUT / 8; ++j) {
                h8 v;
#pragma unroll
                for (int q = 0; q < 4; ++q)
                    v.h[q] = __floats2half2_rn(acc[j * 8 + 2 * q], acc[j * 8 + 2 * q + 1]);
                op[j] = v;
            }
        } else {
            float4* op = (float4*)((float*)outp + (size_t)mynode * DOUT);
#pragma unroll
            for (int j = 0; j < DOUT / 4; ++j) {
                float4 v;
                v.x = acc[4 * j + 0]; v.y = acc[4 * j + 1];
                v.z = acc[4 * j + 2]; v.w = acc[4 * j + 3];
                op[j] = v;
            }
        }
    }
}

// ---------------- launch ----------------

extern "C" void kernel_launch(void* const* d_in, const int* in_sizes, int n_in,
                              void* d_out, int out_size, void* d_ws, size_t ws_size,
                              hipStream_t stream) {
    const float* x   = (const float*)d_in[0];
    const int*   ei  = (const int*)d_in[1];
    const int    E   = in_sizes[1] / 2;
    const int*   src = ei;
    const int*   dst = ei + E;
    const float* W1l = (const float*)d_in[2];
    const float* b1l = (const float*)d_in[3];
    const float* W1r = (const float*)d_in[4];
    const float* W2l = (const float*)d_in[5];
    const float* b2l = (const float*)d_in[6];
    const float* W2r = (const float*)d_in[7];
    const float* W3l = (const float*)d_in[8];
    const float* b3l = (const float*)d_in[9];
    const float* W3r = (const float*)d_in[10];
    const float* Wfc = (const float*)d_in[11];
    const float* bfc = (const float*)d_in[12];
    float* out = (float*)d_out;

    char* p = (char*)d_ws;
    size_t off = 0;
    auto take = [&](size_t bytes) -> void* {
        void* r = p + off;
        off = (off + bytes + 255) & ~(size_t)255;
        return r;
    };
    __half* x16    = (__half*)take((size_t)N_NODES * D * 2);
    __half* A      = (__half*)take((size_t)N_NODES * D * 2);
    __half* H      = (__half*)take((size_t)N_NODES * D * 2);
    float* deg_inv = (float*)take((size_t)N_NODES * 4);
    int*   cnt     = (int*)take((size_t)NPAD * 4);
    int*   row_ptr = (int*)take((size_t)(NPAD + 16) * 4);
    int*   bsums   = (int*)take(256 * 4);
    int*   rank    = (int*)take((size_t)E * 4);
    int*   col     = (int*)take((size_t)E * 4);
    float* Wt1     = (float*)take(128 * 64 * 4);
    float* Wt2     = (float*)take(128 * 64 * 4);
    float* Wt3     = (float*)take(128 * 64 * 4);
    float* Wtfc    = (float*)take(64 * 32 * 4);

    hipMemsetAsync(cnt, 0, (size_t)NPAD * 4, stream);

    k_prep<<<16, 256, 0, stream>>>(W1l, W1r, W2l, W2r, W3l, W3r, Wfc, Wt1, Wt2, Wt3, Wtfc);
    int n4 = N_NODES * D / 4;
    k_cvt<<<(n4 + 255) / 256, 256, 0, stream>>>((const float4*)x, (uint2*)x16, n4);

    int ge8 = (E + 2047) / 2048;
    k_count<<<ge8, 256, 0, stream>>>(dst, cnt, rank, E);
    int nb = NPAD / CHUNK;  // 98
    k_scan1<<<nb, 256, 0, stream>>>(cnt, row_ptr, bsums);
    k_scan2<<<1, 256, 0, stream>>>(bsums, nb);
    k_scan3<<<(NPAD + 255) / 256, 256, 0, stream>>>(row_ptr, bsums, cnt, deg_inv, N_NODES);
    k_scatter<<<ge8, 256, 0, stream>>>(src, dst, row_ptr, rank, col, E);

    int ga = (N_NODES + 3) / 4;        // wave per node (agg)
    int gg = (N_NODES + 127) / 128;    // 782 blocks (gemm)

    // layer 1: x16 -> H
    k_agg16<<<ga, 256, 0, stream>>>(x16, A, row_ptr, col, deg_inv, N_NODES);
    k_gemm<64, true, true, true><<<gg, 128, 0, stream>>>(A, x16, Wt1, b1l, H, N_NODES);
    // layer 2: H -> H (in place)
    k_agg16<<<ga, 256, 0, stream>>>(H, A, row_ptr, col, deg_inv, N_NODES);
    k_gemm<64, true, true, true><<<gg, 128, 0, stream>>>(A, H, Wt2, b2l, H, N_NODES);
    // layer 3: H -> H
    k_agg16<<<ga, 256, 0, stream>>>(H, A, row_ptr, col, deg_inv, N_NODES);
    k_gemm<64, true, true, true><<<gg, 128, 0, stream>>>(A, H, Wt3, b3l, H, N_NODES);
    // final fc
    k_gemm<32, false, false, false><<<gg, 128, 0, stream>>>(H, nullptr, Wtfc, bfc, out, N_NODES);
}

// Round 5
// 370.516 us; speedup vs baseline: 1.9013x; 1.1753x over previous
//
#include <hip/hip_runtime.h>
#include <hip/hip_fp16.h>

#define N_NODES 100000
#define D 64
#define BR 256                     // nodes per bucket
#define NB 391                     // ceil(N_NODES / BR)
#define ECH 4096                   // edges per hist/partition block

struct alignas(16) h8 { __half2 h[4]; };

// ---------------- x -> fp16 ----------------
__global__ __launch_bounds__(256) void k_cvt(const float4* __restrict__ x,
                                             uint2* __restrict__ y, int n4) {
    int i = blockIdx.x * 256 + threadIdx.x;
    if (i < n4) {
        float4 v = x[i];
        union { __half2 h[2]; uint2 u; } pk;
        pk.h[0] = __floats2half2_rn(v.x, v.y);
        pk.h[1] = __floats2half2_rn(v.z, v.w);
        y[i] = pk.u;
    }
}

// ---------------- CSR build (atomic-free at memory side) ----------------

// A: per-block LDS histogram over NB coarse buckets; histT[bucket][block]
__global__ __launch_bounds__(256) void k_hist(const int* __restrict__ dst,
                                              int* __restrict__ histT,
                                              int E, int ga) {
    __shared__ int h[NB];
    int blk = blockIdx.x, tid = threadIdx.x;
    for (int i = tid; i < NB; i += 256) h[i] = 0;
    __syncthreads();
    int base = blk * ECH;
    int lim = E - base; if (lim > ECH) lim = ECH;
    for (int i = tid; i < lim; i += 256)
        atomicAdd(&h[dst[base + i] >> 8], 1);
    __syncthreads();
    for (int i = tid; i < NB; i += 256)
        histT[i * ga + blk] = h[i];
}

// B1: per-block exclusive scan over 1024 ints; partial scan + block sum.
__global__ __launch_bounds__(256) void k_scan1(const int* __restrict__ cnt,
                                               int* __restrict__ part,
                                               int* __restrict__ bsums) {
    __shared__ int s[256];
    int tid = threadIdx.x;
    int i4 = blockIdx.x * 256 + tid;
    int4 v = reinterpret_cast<const int4*>(cnt)[i4];
    int tsum = v.x + v.y + v.z + v.w;
    s[tid] = tsum;
    __syncthreads();
    for (int off = 1; off < 256; off <<= 1) {
        int t = 0;
        if (tid >= off) t = s[tid - off];
        __syncthreads();
        if (tid >= off) s[tid] += t;
        __syncthreads();
    }
    int excl = tid ? s[tid - 1] : 0;
    if (tid == 255) bsums[blockIdx.x] = s[255];
    int4 o;
    o.x = excl;
    o.y = o.x + v.x;
    o.z = o.y + v.y;
    o.w = o.z + v.z;
    reinterpret_cast<int4*>(part)[i4] = o;
}

// B2: exclusive scan of the (<=256) block sums, in place.
__global__ __launch_bounds__(256) void k_scan2(int* __restrict__ bsums, int nb) {
    __shared__ int s[256];
    int tid = threadIdx.x;
    int v = (tid < nb) ? bsums[tid] : 0;
    s[tid] = v;
    __syncthreads();
    for (int off = 1; off < 256; off <<= 1) {
        int t = 0;
        if (tid >= off) t = s[tid - off];
        __syncthreads();
        if (tid >= off) s[tid] += t;
        __syncthreads();
    }
    if (tid < nb) bsums[tid] = tid ? s[tid - 1] : 0;
}

// B3: add scanned block sums.
__global__ __launch_bounds__(256) void k_scanadd(int* __restrict__ a,
                                                 const int* __restrict__ bsums, int n) {
    int i = blockIdx.x * 256 + threadIdx.x;
    if (i < n) a[i] += bsums[i >> 10];
}

// C: partition (src,dst) into bucket-major order; LDS cursors, no global atomics.
__global__ __launch_bounds__(256) void k_part(const int* __restrict__ src,
                                              const int* __restrict__ dst,
                                              const int* __restrict__ offs,
                                              int2* __restrict__ bedge,
                                              int E, int ga) {
    __shared__ int o[NB];
    int blk = blockIdx.x, tid = threadIdx.x;
    for (int i = tid; i < NB; i += 256) o[i] = offs[i * ga + blk];
    __syncthreads();
    int base = blk * ECH;
    int lim = E - base; if (lim > ECH) lim = ECH;
    for (int i = tid; i < lim; i += 256) {
        int e = base + i;
        int d = dst[e];
        int pos = atomicAdd(&o[d >> 8], 1);
        bedge[pos] = make_int2(src[e], d);
    }
}

// D: per-bucket exact CSR: local hist -> block scan -> row_ptr/deg_inv -> col scatter.
__global__ __launch_bounds__(256) void k_csr(const int2* __restrict__ bedge,
                                             const int* __restrict__ offs,
                                             int* __restrict__ col,
                                             int* __restrict__ row_ptr,
                                             float* __restrict__ deg_inv,
                                             int E, int ga) {
    __shared__ int lcnt[BR];
    __shared__ int stmp[BR];
    __shared__ int lcur[BR];
    int b = blockIdx.x, tid = threadIdx.x;
    int beg = offs[b * ga];
    int end = (b + 1 < NB) ? offs[(b + 1) * ga] : E;
    int nbase = b * BR;
    lcnt[tid] = 0;
    __syncthreads();
    for (int e = beg + tid; e < end; e += 256)
        atomicAdd(&lcnt[bedge[e].y - nbase], 1);
    __syncthreads();
    int v = lcnt[tid];
    stmp[tid] = v;
    __syncthreads();
    for (int off = 1; off < 256; off <<= 1) {
        int t = 0;
        if (tid >= off) t = stmp[tid - off];
        __syncthreads();
        if (tid >= off) stmp[tid] += t;
        __syncthreads();
    }
    int ex = tid ? stmp[tid - 1] : 0;
    int slot = beg + ex;
    lcur[tid] = slot;
    int node = nbase + tid;
    if (node < N_NODES) {
        row_ptr[node] = slot;
        deg_inv[node] = 1.0f / (float)(v > 1 ? v : 1);
    }
    if (b == NB - 1 && tid == 255) row_ptr[N_NODES] = E;
    __syncthreads();
    for (int e = beg + tid; e < end; e += 256) {
        int2 ed = bedge[e];
        int pos = atomicAdd(&lcur[ed.y - nbase], 1);
        col[pos] = ed.x;
    }
}

// ---------------- mean aggregation (fp16 table): one wave per node ----------------

__global__ __launch_bounds__(256) void k_agg16(const __half* __restrict__ xin,
                                               __half* __restrict__ agg,
                                               const int* __restrict__ row_ptr,
                                               const int* __restrict__ col,
                                               const float* __restrict__ deg_inv, int n) {
    int node = blockIdx.x * 4 + (threadIdx.x >> 6);
    int lane = threadIdx.x & 63;
    if (node >= n) return;
    int beg = row_ptr[node], end = row_ptr[node + 1];
    int deg = end - beg;
    int dc = deg < 64 ? deg : 64;
    int myc = 0;
    if (lane < dc) myc = col[beg + lane];
    float acc = 0.f;
    int j = 0;
    for (; j + 8 <= dc; j += 8) {
        int s0 = __shfl(myc, j + 0), s1 = __shfl(myc, j + 1);
        int s2 = __shfl(myc, j + 2), s3 = __shfl(myc, j + 3);
        int s4 = __shfl(myc, j + 4), s5 = __shfl(myc, j + 5);
        int s6 = __shfl(myc, j + 6), s7 = __shfl(myc, j + 7);
        float a0 = __half2float(xin[s0 * D + lane]);
        float a1 = __half2float(xin[s1 * D + lane]);
        float a2 = __half2float(xin[s2 * D + lane]);
        float a3 = __half2float(xin[s3 * D + lane]);
        float a4 = __half2float(xin[s4 * D + lane]);
        float a5 = __half2float(xin[s5 * D + lane]);
        float a6 = __half2float(xin[s6 * D + lane]);
        float a7 = __half2float(xin[s7 * D + lane]);
        acc += ((a0 + a1) + (a2 + a3)) + ((a4 + a5) + (a6 + a7));
    }
    for (; j < dc; ++j) acc += __half2float(xin[__shfl(myc, j) * D + lane]);
    for (int e = beg + 64; e < end; ++e) acc += __half2float(xin[col[e] * D + lane]);
    agg[node * D + lane] = __float2half(acc * deg_inv[node]);
}

// ---------------- weight prep: Wt[k][o] = W[o][k], Wl/Wr stacked along k ----------------

__global__ __launch_bounds__(256) void k_prep(const float* __restrict__ Wl1, const float* __restrict__ Wr1,
                                              const float* __restrict__ Wl2, const float* __restrict__ Wr2,
                                              const float* __restrict__ Wl3, const float* __restrict__ Wr3,
                                              const float* __restrict__ Wfc,
                                              float* __restrict__ Wt1, float* __restrict__ Wt2,
                                              float* __restrict__ Wt3, float* __restrict__ Wtfc) {
    int t = blockIdx.x * 256 + threadIdx.x;
    if (t < 4096) {
        int k = t >> 6, o = t & 63;
        Wt1[k * 64 + o] = Wl1[o * 64 + k];
        Wt1[(k + 64) * 64 + o] = Wr1[o * 64 + k];
        Wt2[k * 64 + o] = Wl2[o * 64 + k];
        Wt2[(k + 64) * 64 + o] = Wr2[o * 64 + k];
        Wt3[k * 64 + o] = Wl3[o * 64 + k];
        Wt3[(k + 64) * 64 + o] = Wr3[o * 64 + k];
        if (o < 32) Wtfc[k * 32 + o] = Wfc[o * 64 + k];
    }
}

// ---------------- fused linear as register-tiled GEMM (fp16 activations) ----------------

template <int DOUT, bool RELU, bool TWO, bool HOUT>
__global__ __launch_bounds__(128) void k_gemm(const __half* __restrict__ A,
                                              const __half* __restrict__ X,
                                              const float* __restrict__ Wt,
                                              const float* __restrict__ bias,
                                              void* __restrict__ outp, int n) {
    constexpr int NCH = TWO ? 4 : 2;   // K chunks of 32
    __shared__ float Xt[32][129];
    int tid = threadIdx.x;             // 0..127, per-thread node
    int mynode = blockIdx.x * 128 + tid;
    bool act = mynode < n;

    float acc[DOUT];
#pragma unroll
    for (int o = 0; o < DOUT; ++o) acc[o] = bias[o];   // uniform -> s_load

    for (int ch = 0; ch < NCH; ++ch) {
        const __half* srcp = (TWO && ch >= 2) ? X : A;
        int kbase = (ch & (TWO ? 1 : 3)) * 32;
        __syncthreads();
        if (act) {
            const h8* rp = (const h8*)(srcp + (size_t)mynode * D + kbase);
#pragma unroll
            for (int j = 0; j < 4; ++j) {
                h8 v = rp[j];
#pragma unroll
                for (int q = 0; q < 4; ++q) {
                    float2 f = __half22float2(v.h[q]);
                    Xt[j * 8 + q * 2 + 0][tid] = f.x;
                    Xt[j * 8 + q * 2 + 1][tid] = f.y;
                }
            }
        }
        __syncthreads();
        const float* wrow = Wt + (size_t)ch * 32 * DOUT;
#pragma unroll 2
        for (int k = 0; k < 32; ++k) {
            float xv = Xt[k][tid];
#pragma unroll
            for (int o = 0; o < DOUT; ++o)
                acc[o] = fmaf(xv, wrow[k * DOUT + o], acc[o]);  // wrow uniform -> s_load
        }
    }
    if (act) {
        if (RELU) {
#pragma unroll
            for (int o = 0; o < DOUT; ++o) acc[o] = fmaxf(acc[o], 0.f);
        }
        if (HOUT) {
            h8* op = (h8*)((__half*)outp + (size_t)mynode * DOUT);
#pragma unroll
            for (int j = 0; j < DOUT / 8; ++j) {
                h8 v;
#pragma unroll
                for (int q = 0; q < 4; ++q)
                    v.h[q] = __floats2half2_rn(acc[j * 8 + 2 * q], acc[j * 8 + 2 * q + 1]);
                op[j] = v;
            }
        } else {
            float4* op = (float4*)((float*)outp + (size_t)mynode * DOUT);
#pragma unroll
            for (int j = 0; j < DOUT / 4; ++j) {
                float4 v;
                v.x = acc[4 * j + 0]; v.y = acc[4 * j + 1];
                v.z = acc[4 * j + 2]; v.w = acc[4 * j + 3];
                op[j] = v;
            }
        }
    }
}

// ---------------- launch ----------------

extern "C" void kernel_launch(void* const* d_in, const int* in_sizes, int n_in,
                              void* d_out, int out_size, void* d_ws, size_t ws_size,
                              hipStream_t stream) {
    const float* x   = (const float*)d_in[0];
    const int*   ei  = (const int*)d_in[1];
    const int    E   = in_sizes[1] / 2;
    const int*   src = ei;
    const int*   dst = ei + E;
    const float* W1l = (const float*)d_in[2];
    const float* b1l = (const float*)d_in[3];
    const float* W1r = (const float*)d_in[4];
    const float* W2l = (const float*)d_in[5];
    const float* b2l = (const float*)d_in[6];
    const float* W2r = (const float*)d_in[7];
    const float* W3l = (const float*)d_in[8];
    const float* b3l = (const float*)d_in[9];
    const float* W3r = (const float*)d_in[10];
    const float* Wfc = (const float*)d_in[11];
    const float* bfc = (const float*)d_in[12];
    float* out = (float*)d_out;

    const int ga      = (E + ECH - 1) / ECH;            // hist/partition blocks
    const int entries = NB * ga;
    const int padded  = (entries + 1023) & ~1023;
    const int nb2     = padded / 1024;                  // scan1 blocks (<=256)

    char* p = (char*)d_ws;
    size_t off = 0;
    auto take = [&](size_t bytes) -> void* {
        void* r = p + off;
        off = (off + bytes + 255) & ~(size_t)255;
        return r;
    };
    __half* x16    = (__half*)take((size_t)N_NODES * D * 2);
    __half* A      = (__half*)take((size_t)N_NODES * D * 2);
    __half* H      = (__half*)take((size_t)N_NODES * D * 2);
    float* deg_inv = (float*)take((size_t)N_NODES * 4);
    int*   row_ptr = (int*)take((size_t)(N_NODES + 16) * 4);
    int*   histT   = (int*)take((size_t)padded * 4);
    int*   offs    = (int*)take((size_t)padded * 4);
    int*   bsums   = (int*)take(256 * 4);
    int2*  bedge   = (int2*)take((size_t)E * 8);
    int*   col     = (int*)take((size_t)E * 4);
    float* Wt1     = (float*)take(128 * 64 * 4);
    float* Wt2     = (float*)take(128 * 64 * 4);
    float* Wt3     = (float*)take(128 * 64 * 4);
    float* Wtfc    = (float*)take(64 * 32 * 4);

    k_prep<<<16, 256, 0, stream>>>(W1l, W1r, W2l, W2r, W3l, W3r, Wfc, Wt1, Wt2, Wt3, Wtfc);
    int n4 = N_NODES * D / 4;
    k_cvt<<<(n4 + 255) / 256, 256, 0, stream>>>((const float4*)x, (uint2*)x16, n4);

    // CSR build: hist -> scan -> partition -> per-bucket CSR (no global atomics)
    hipMemsetAsync(histT, 0, (size_t)padded * 4, stream);
    k_hist<<<ga, 256, 0, stream>>>(dst, histT, E, ga);
    k_scan1<<<nb2, 256, 0, stream>>>(histT, offs, bsums);
    k_scan2<<<1, 256, 0, stream>>>(bsums, nb2);
    k_scanadd<<<(padded + 255) / 256, 256, 0, stream>>>(offs, bsums, padded);
    k_part<<<ga, 256, 0, stream>>>(src, dst, offs, bedge, E, ga);
    k_csr<<<NB, 256, 0, stream>>>(bedge, offs, col, row_ptr, deg_inv, E, ga);

    int gaw = (N_NODES + 3) / 4;       // wave per node (agg)
    int gg = (N_NODES + 127) / 128;    // gemm blocks

    // layer 1: x16 -> H
    k_agg16<<<gaw, 256, 0, stream>>>(x16, A, row_ptr, col, deg_inv, N_NODES);
    k_gemm<64, true, true, true><<<gg, 128, 0, stream>>>(A, x16, Wt1, b1l, H, N_NODES);
    // layer 2: H -> H (in place)
    k_agg16<<<gaw, 256, 0, stream>>>(H, A, row_ptr, col, deg_inv, N_NODES);
    k_gemm<64, true, true, true><<<gg, 128, 0, stream>>>(A, H, Wt2, b2l, H, N_NODES);
    // layer 3: H -> H
    k_agg16<<<gaw, 256, 0, stream>>>(H, A, row_ptr, col, deg_inv, N_NODES);
    k_gemm<64, true, true, true><<<gg, 128, 0, stream>>>(A, H, Wt3, b3l, H, N_NODES);
    // final fc
    k_gemm<32, false, false, false><<<gg, 128, 0, stream>>>(H, nullptr, Wtfc, bfc, out, N_NODES);
}

// Round 6
// 217.203 us; speedup vs baseline: 3.2434x; 1.7059x over previous
//
#include <hip/hip_runtime.h>
#include <hip/hip_fp16.h>

#define N_NODES 100000
#define D 64
#define BR 256                     // nodes per bucket
#define NB 391                     // ceil(N_NODES / BR)
#define ECH 4096                   // edges per hist/partition block
#define NROWPAD 100096             // NB*BR, multiple of 64 (gemm tile pad)

typedef _Float16 f16x8 __attribute__((ext_vector_type(8)));
typedef float f32x4 __attribute__((ext_vector_type(4)));

// ---------------- x -> fp16 ----------------
__global__ __launch_bounds__(256) void k_cvt(const float4* __restrict__ x,
                                             uint2* __restrict__ y, int n4) {
    int i = blockIdx.x * 256 + threadIdx.x;
    if (i < n4) {
        float4 v = x[i];
        union { __half2 h[2]; uint2 u; } pk;
        pk.h[0] = __floats2half2_rn(v.x, v.y);
        pk.h[1] = __floats2half2_rn(v.z, v.w);
        y[i] = pk.u;
    }
}

// ---------------- weight prep: MFMA B-fragment order, fp16 ----------------
// frag f=(kt*NT+nt): elem (lane,i) = W_cat[kt*32+(lane>>4)*8+i][nt*16+(lane&15)]
__global__ __launch_bounds__(256) void k_prep(const float* __restrict__ Wl1, const float* __restrict__ Wr1,
                                              const float* __restrict__ Wl2, const float* __restrict__ Wr2,
                                              const float* __restrict__ Wl3, const float* __restrict__ Wr3,
                                              const float* __restrict__ Wfc,
                                              __half* __restrict__ Wf1, __half* __restrict__ Wf2,
                                              __half* __restrict__ Wf3, __half* __restrict__ Wffc) {
    int t = blockIdx.x * 256 + threadIdx.x;
    if (t < 24576) {                       // 3 layers x 16 frags x 512
        int layer = t / 8192;
        int r = t % 8192;
        int f = r >> 9, rem = r & 511;
        int lane = rem >> 3, i = rem & 7;
        int kt = f >> 2, nt = f & 3;
        int k = kt * 32 + (lane >> 4) * 8 + i;   // 0..127 over [Wl|Wr]
        int o = nt * 16 + (lane & 15);
        const float* Wl = layer == 0 ? Wl1 : layer == 1 ? Wl2 : Wl3;
        const float* Wr = layer == 0 ? Wr1 : layer == 1 ? Wr2 : Wr3;
        float v = (k < 64) ? Wl[o * 64 + k] : Wr[o * 64 + (k - 64)];
        __half* Wf = layer == 0 ? Wf1 : layer == 1 ? Wf2 : Wf3;
        Wf[r] = __float2half(v);
    } else if (t < 26624) {                // fc: 4 frags x 512
        int r = t - 24576;
        int f = r >> 9, rem = r & 511;
        int lane = rem >> 3, i = rem & 7;
        int kt = f >> 1, nt = f & 1;
        int k = kt * 32 + (lane >> 4) * 8 + i;
        int o = nt * 16 + (lane & 15);
        Wffc[r] = __float2half(Wfc[o * 64 + k]);
    }
}

// ---------------- CSR build (no global atomics) ----------------

__global__ __launch_bounds__(256) void k_hist(const int* __restrict__ dst,
                                              int* __restrict__ histT,
                                              int E, int ga) {
    __shared__ int h[NB];
    int blk = blockIdx.x, tid = threadIdx.x;
    for (int i = tid; i < NB; i += 256) h[i] = 0;
    __syncthreads();
    int base = blk * ECH;
    int lim = E - base; if (lim > ECH) lim = ECH;
    for (int i = tid; i < lim; i += 256)
        atomicAdd(&h[dst[base + i] >> 8], 1);
    __syncthreads();
    for (int i = tid; i < NB; i += 256)
        histT[i * ga + blk] = h[i];
}

__global__ __launch_bounds__(256) void k_scan1(const int* __restrict__ cnt,
                                               int* __restrict__ part,
                                               int* __restrict__ bsums) {
    __shared__ int s[256];
    int tid = threadIdx.x;
    int i4 = blockIdx.x * 256 + tid;
    int4 v = reinterpret_cast<const int4*>(cnt)[i4];
    int tsum = v.x + v.y + v.z + v.w;
    s[tid] = tsum;
    __syncthreads();
    for (int off = 1; off < 256; off <<= 1) {
        int t = 0;
        if (tid >= off) t = s[tid - off];
        __syncthreads();
        if (tid >= off) s[tid] += t;
        __syncthreads();
    }
    int excl = tid ? s[tid - 1] : 0;
    if (tid == 255) bsums[blockIdx.x] = s[255];
    int4 o;
    o.x = excl;
    o.y = o.x + v.x;
    o.z = o.y + v.y;
    o.w = o.z + v.z;
    reinterpret_cast<int4*>(part)[i4] = o;
}

__global__ __launch_bounds__(256) void k_scan2(int* __restrict__ bsums, int nb) {
    __shared__ int s[256];
    int tid = threadIdx.x;
    int v = (tid < nb) ? bsums[tid] : 0;
    s[tid] = v;
    __syncthreads();
    for (int off = 1; off < 256; off <<= 1) {
        int t = 0;
        if (tid >= off) t = s[tid - off];
        __syncthreads();
        if (tid >= off) s[tid] += t;
        __syncthreads();
    }
    if (tid < nb) bsums[tid] = tid ? s[tid - 1] : 0;
}

// partition into bucket-major, packed edge = src | (ldst<<17); bsums folded in
__global__ __launch_bounds__(256) void k_part(const int* __restrict__ src,
                                              const int* __restrict__ dst,
                                              const int* __restrict__ offs,
                                              const int* __restrict__ bsums,
                                              int* __restrict__ bedge,
                                              int E, int ga) {
    __shared__ int o[NB];
    int blk = blockIdx.x, tid = threadIdx.x;
    for (int i = tid; i < NB; i += 256) {
        int ent = i * ga + blk;
        o[i] = offs[ent] + bsums[ent >> 10];
    }
    __syncthreads();
    int base = blk * ECH;
    int lim = E - base; if (lim > ECH) lim = ECH;
    for (int i = tid; i < lim; i += 256) {
        int e = base + i;
        int d = dst[e];
        int pos = atomicAdd(&o[d >> 8], 1);
        bedge[pos] = src[e] | ((d & 255) << 17);
    }
}

__global__ __launch_bounds__(256) void k_csr(const int* __restrict__ bedge,
                                             const int* __restrict__ offs,
                                             const int* __restrict__ bsums,
                                             int* __restrict__ col,
                                             int* __restrict__ row_ptr,
                                             float* __restrict__ deg_inv,
                                             int E, int ga) {
    __shared__ int lcnt[BR];
    __shared__ int stmp[BR];
    __shared__ int lcur[BR];
    int b = blockIdx.x, tid = threadIdx.x;
    int e0 = b * ga;
    int beg = offs[e0] + bsums[e0 >> 10];
    int end = E;
    if (b + 1 < NB) {
        int e1 = (b + 1) * ga;
        end = offs[e1] + bsums[e1 >> 10];
    }
    int nbase = b * BR;
    lcnt[tid] = 0;
    __syncthreads();
    for (int e = beg + tid; e < end; e += 256)
        atomicAdd(&lcnt[bedge[e] >> 17], 1);
    __syncthreads();
    int v = lcnt[tid];
    stmp[tid] = v;
    __syncthreads();
    for (int off = 1; off < 256; off <<= 1) {
        int t = 0;
        if (tid >= off) t = stmp[tid - off];
        __syncthreads();
        if (tid >= off) stmp[tid] += t;
        __syncthreads();
    }
    int ex = tid ? stmp[tid - 1] : 0;
    int slot = beg + ex;
    lcur[tid] = slot;
    int node = nbase + tid;
    if (node < N_NODES) {
        row_ptr[node] = slot;
        deg_inv[node] = 1.0f / (float)(v > 1 ? v : 1);
    }
    if (b == NB - 1 && tid == 255) row_ptr[N_NODES] = E;
    __syncthreads();
    for (int e = beg + tid; e < end; e += 256) {
        int ed = bedge[e];
        int pos = atomicAdd(&lcur[ed >> 17], 1);
        col[pos] = ed & 0x1FFFF;
    }
}

// ---------------- mean aggregation: wave/node, half2 lanes, 2 rows/load ----------------

__global__ __launch_bounds__(256) void k_agg2(const __half* __restrict__ xin,
                                              __half* __restrict__ agg,
                                              const int* __restrict__ row_ptr,
                                              const int* __restrict__ col,
                                              const float* __restrict__ deg_inv, int n) {
    int node = blockIdx.x * 4 + (threadIdx.x >> 6);
    int lane = threadIdx.x & 63;
    if (node >= n) return;
    int beg = row_ptr[node], end = row_ptr[node + 1];
    int deg = end - beg;
    int dc = deg < 64 ? deg : 64;
    int hf = lane >> 5, li = lane & 31;
    int myc = 0;
    if (lane < dc) myc = col[beg + lane];
    const __half2* x2 = (const __half2*)xin;
    float ax = 0.f, ay = 0.f;
    for (int j = 0; j < dc; j += 16) {
#pragma unroll
        for (int p = 0; p < 8; ++p) {
            int ei = j + 2 * p + hf;
            int ec = ei < dc ? ei : dc - 1;        // clamp (dc>0 here)
            int idx = __shfl(myc, ec);
            float2 f = __half22float2(x2[(size_t)idx * 32 + li]);
            if (ei < dc) { ax += f.x; ay += f.y; }
        }
    }
    for (int e = beg + 64; e < end; e += 2) {       // deg>64 tail (rare)
        int i0 = col[e];
        int i1 = (e + 1 < end) ? col[e + 1] : -1;
        int idx = hf ? i1 : i0;
        if (idx >= 0) {
            float2 f = __half22float2(x2[(size_t)idx * 32 + li]);
            ax += f.x; ay += f.y;
        }
    }
    ax += __shfl_xor(ax, 32);
    ay += __shfl_xor(ay, 32);
    if (lane < 32) {
        float di = deg_inv[node];
        ((__half2*)agg)[(size_t)node * 32 + li] = __floats2half2_rn(ax * di, ay * di);
    }
}

// ---------------- MFMA gemm: H = (relu)([A|X] @ W_cat + bias) ----------------
// wave: 16 nodes; A-frag row=l&15, k=(l>>4)*8+i; C/D col=l&15, row=(l>>4)*4+q.
// In-place (out==X) safe: wave reads/writes only its own 16 rows, loads precede stores.

template <int KT, int NT, bool RELU, bool TWO, bool HOUT>
__global__ __launch_bounds__(256) void k_mgemm(const __half* __restrict__ A,
                                               const __half* __restrict__ X,
                                               const __half* __restrict__ Wf,
                                               const float* __restrict__ bias,
                                               void* __restrict__ outp, int n) {
    int l = threadIdx.x & 63;
    int wv = threadIdx.x >> 6;
    int m0 = blockIdx.x * 64 + wv * 16;
    int rowA = l & 15;
    int kg = l >> 4;
    const f16x8* wf8 = (const f16x8*)Wf;
    f16x8 b[KT][NT];
#pragma unroll
    for (int kt = 0; kt < KT; ++kt)
#pragma unroll
        for (int nt = 0; nt < NT; ++nt)
            b[kt][nt] = wf8[(kt * NT + nt) * 64 + l];
    f32x4 acc[NT];
#pragma unroll
    for (int nt = 0; nt < NT; ++nt) {
        float bs = bias[nt * 16 + rowA];
        acc[nt] = (f32x4){bs, bs, bs, bs};
    }
#pragma unroll
    for (int kt = 0; kt < KT; ++kt) {
        const __half* sp = (TWO && kt >= KT / 2) ? X : A;
        int ko = (TWO ? (kt & (KT / 2 - 1)) : kt) * 32;
        f16x8 a = *(const f16x8*)(sp + (size_t)(m0 + rowA) * D + ko + kg * 8);
#pragma unroll
        for (int nt = 0; nt < NT; ++nt)
            acc[nt] = __builtin_amdgcn_mfma_f32_16x16x32_f16(a, b[kt][nt], acc[nt], 0, 0, 0);
    }
#pragma unroll
    for (int nt = 0; nt < NT; ++nt)
#pragma unroll
        for (int q = 0; q < 4; ++q) {
            int node = m0 + kg * 4 + q;
            float v = acc[nt][q];
            if (RELU) v = fmaxf(v, 0.f);
            if (node < n) {
                if (HOUT)
                    ((__half*)outp)[(size_t)node * D + nt * 16 + rowA] = __float2half(v);
                else
                    ((float*)outp)[(size_t)node * (NT * 16) + nt * 16 + rowA] = v;
            }
        }
}

// ---------------- launch ----------------

extern "C" void kernel_launch(void* const* d_in, const int* in_sizes, int n_in,
                              void* d_out, int out_size, void* d_ws, size_t ws_size,
                              hipStream_t stream) {
    const float* x   = (const float*)d_in[0];
    const int*   ei  = (const int*)d_in[1];
    const int    E   = in_sizes[1] / 2;
    const int*   src = ei;
    const int*   dst = ei + E;
    const float* W1l = (const float*)d_in[2];
    const float* b1l = (const float*)d_in[3];
    const float* W1r = (const float*)d_in[4];
    const float* W2l = (const float*)d_in[5];
    const float* b2l = (const float*)d_in[6];
    const float* W2r = (const float*)d_in[7];
    const float* W3l = (const float*)d_in[8];
    const float* b3l = (const float*)d_in[9];
    const float* W3r = (const float*)d_in[10];
    const float* Wfc = (const float*)d_in[11];
    const float* bfc = (const float*)d_in[12];
    float* out = (float*)d_out;

    const int ga      = (E + ECH - 1) / ECH;
    const int entries = NB * ga;
    const int padded  = (entries + 1023) & ~1023;
    const int nb2     = padded / 1024;

    char* p = (char*)d_ws;
    size_t off = 0;
    auto take = [&](size_t bytes) -> void* {
        void* r = p + off;
        off = (off + bytes + 255) & ~(size_t)255;
        return r;
    };
    __half* x16    = (__half*)take((size_t)NROWPAD * D * 2);
    __half* A      = (__half*)take((size_t)NROWPAD * D * 2);
    __half* H      = (__half*)take((size_t)NROWPAD * D * 2);
    float* deg_inv = (float*)take((size_t)N_NODES * 4);
    int*   row_ptr = (int*)take((size_t)(N_NODES + 16) * 4);
    int*   histT   = (int*)take((size_t)padded * 4);
    int*   offs    = (int*)take((size_t)padded * 4);
    int*   bsums   = (int*)take(256 * 4);
    int*   bedge   = (int*)take((size_t)E * 4);
    int*   col     = (int*)take((size_t)E * 4);
    __half* Wf1    = (__half*)take(8192 * 2);
    __half* Wf2    = (__half*)take(8192 * 2);
    __half* Wf3    = (__half*)take(8192 * 2);
    __half* Wffc   = (__half*)take(2048 * 2);

    k_prep<<<104, 256, 0, stream>>>(W1l, W1r, W2l, W2r, W3l, W3r, Wfc, Wf1, Wf2, Wf3, Wffc);
    int n4 = N_NODES * D / 4;
    k_cvt<<<(n4 + 255) / 256, 256, 0, stream>>>((const float4*)x, (uint2*)x16, n4);

    hipMemsetAsync(histT, 0, (size_t)padded * 4, stream);
    k_hist<<<ga, 256, 0, stream>>>(dst, histT, E, ga);
    k_scan1<<<nb2, 256, 0, stream>>>(histT, offs, bsums);
    k_scan2<<<1, 256, 0, stream>>>(bsums, nb2);
    k_part<<<ga, 256, 0, stream>>>(src, dst, offs, bsums, bedge, E, ga);
    k_csr<<<NB, 256, 0, stream>>>(bedge, offs, bsums, col, row_ptr, deg_inv, E, ga);

    int gaw = (N_NODES + 3) / 4;       // agg: wave per node
    int gg  = NROWPAD / 64;            // gemm: 64 nodes per block

    // layer 1: x16 -> H
    k_agg2<<<gaw, 256, 0, stream>>>(x16, A, row_ptr, col, deg_inv, N_NODES);
    k_mgemm<4, 4, true, true, true><<<gg, 256, 0, stream>>>(A, x16, Wf1, b1l, H, N_NODES);
    // layer 2: H -> H (in place)
    k_agg2<<<gaw, 256, 0, stream>>>(H, A, row_ptr, col, deg_inv, N_NODES);
    k_mgemm<4, 4, true, true, true><<<gg, 256, 0, stream>>>(A, H, Wf2, b2l, H, N_NODES);
    // layer 3: H -> H
    k_agg2<<<gaw, 256, 0, stream>>>(H, A, row_ptr, col, deg_inv, N_NODES);
    k_mgemm<4, 4, true, true, true><<<gg, 256, 0, stream>>>(A, H, Wf3, b3l, H, N_NODES);
    // final fc: H -> out (f32)
    k_mgemm<2, 2, false, false, false><<<gg, 256, 0, stream>>>(H, nullptr, Wffc, bfc, out, N_NODES);
}